// Round 8
// baseline (177.950 us; speedup 1.0000x reference)
//
#include <hip/hip_runtime.h>
#include <hip/hip_fp16.h>
#include <math.h>

#define NN 30000
#define KK 32
#define FF 256
#define DD 128
#define NB 938   // ceil(30000/32)

typedef _Float16 f16x8 __attribute__((ext_vector_type(8)));
typedef float f32x4v __attribute__((ext_vector_type(4)));

__device__ __forceinline__ float seluf(float x) {
    const float scale = 1.0507009873554804934193349852946f;
    const float alpha = 1.6732632423543772848170429916717f;
    return x > 0.f ? scale * x : scale * alpha * expm1f(x);
}

__device__ __forceinline__ float waveReduceSum(float v) {
#pragma unroll
    for (int m = 1; m < 64; m <<= 1) v += __shfl_xor(v, m, 64);
    return v;
}

// -------- kernel 0: transposed f16 weight tables ---------------------------
__global__ __launch_bounds__(256) void k_prep(
    const float* __restrict__ W, const float* __restrict__ M,
    _Float16* __restrict__ Wt, _Float16* __restrict__ Lt)
{
    const int b = blockIdx.x, t = threadIdx.x;
    if (b < 128) {
        Wt[b * FF + t] = (_Float16)W[t * DD + b];
    } else if (t < 128) {
        const int c = b - 128, k = t;
        const float v = (k == 0 && c == 0) ? 1.f
                      : ((k >= 1 && c >= 1) ? M[(k - 1) * 127 + (c - 1)] : 0.f);
        Lt[c * DD + k] = (_Float16)v;
    }
}

// -------- kernel 1: h = normalize(exp_map_zero(selu(x @ W + b))) -----------
__global__ __launch_bounds__(256) void k_lin_exp(
    const float* __restrict__ x, const _Float16* __restrict__ Wt,
    const float* __restrict__ b, float* __restrict__ h)
{
    __shared__ float red[4][16];
    const int wv_ = threadIdx.x >> 6;
    const int lane = threadIdx.x & 63;
    const int g = lane >> 4, c16 = lane & 15;
    const int baseRow = blockIdx.x * 32 + (wv_ >> 1) * 16;
    const int nb = (wv_ & 1) * 4;
    const int arow = baseRow + c16;
    const bool rowOK = arow < NN;

    float4 f[16];
    const float4* xp = (const float4*)(x + (size_t)arow * FF) + g * 2;
    if (rowOK) {
#pragma unroll
        for (int ks = 0; ks < 8; ++ks) {
            f[2 * ks]     = xp[ks * 8];
            f[2 * ks + 1] = xp[ks * 8 + 1];
        }
    } else {
#pragma unroll
        for (int i = 0; i < 16; ++i) f[i] = float4{0.f, 0.f, 0.f, 0.f};
    }
    f16x8 ahi[8], alo[8];
#pragma unroll
    for (int ks = 0; ks < 8; ++ks) {
        const float q[8] = {f[2 * ks].x, f[2 * ks].y, f[2 * ks].z, f[2 * ks].w,
                            f[2 * ks + 1].x, f[2 * ks + 1].y, f[2 * ks + 1].z, f[2 * ks + 1].w};
#pragma unroll
        for (int j = 0; j < 8; ++j) {
            ahi[ks][j] = (_Float16)q[j];
            alo[ks][j] = (_Float16)(q[j] - (float)ahi[ks][j]);
        }
    }

    f32x4v acc[4];
#pragma unroll
    for (int n = 0; n < 4; ++n) acc[n] = f32x4v{0.f, 0.f, 0.f, 0.f};
#pragma unroll
    for (int ks = 0; ks < 8; ++ks) {
#pragma unroll
        for (int n = 0; n < 4; ++n) {
            const f16x8 bh = *(const f16x8*)(Wt + (size_t)((nb + n) * 16 + c16) * FF + ks * 32 + g * 8);
            acc[n] = __builtin_amdgcn_mfma_f32_16x16x32_f16(ahi[ks], bh, acc[n], 0, 0, 0);
            acc[n] = __builtin_amdgcn_mfma_f32_16x16x32_f16(alo[ks], bh, acc[n], 0, 0, 0);
        }
    }

    float bias[4];
#pragma unroll
    for (int n = 0; n < 4; ++n) bias[n] = b[(nb + n) * 16 + c16];

    float vv[4][4];
#pragma unroll
    for (int r = 0; r < 4; ++r) {
        float part = 0.f;
#pragma unroll
        for (int n = 0; n < 4; ++n) {
            vv[r][n] = seluf(acc[n][r] + bias[n]);
            float sq = vv[r][n] * vv[r][n];
            if (nb == 0 && n == 0 && c16 == 0) sq = 0.f;
            part += sq;
        }
#pragma unroll
        for (int m = 1; m < 16; m <<= 1) part += __shfl_xor(part, m, 64);
        if (c16 == 0) red[wv_][4 * g + r] = part;
    }
    __syncthreads();
#pragma unroll
    for (int r = 0; r < 4; ++r) {
        const int row = baseRow + 4 * g + r;
        const float ldv = red[wv_][4 * g + r] + red[wv_ ^ 1][4 * g + r];
        const float nd = sqrtf(fmaxf(ldv + 1e-9f, 1e-10f));
        const float t  = fminf(nd, 1.0f);
        const float sc = sinhf(t) / nd;
        const float tm = sqrtf(1.f + sc * sc * ldv);
        if (row < NN) {
#pragma unroll
            for (int n = 0; n < 4; ++n) {
                const float o = (nb == 0 && n == 0 && c16 == 0) ? tm : sc * vv[r][n];
                h[(size_t)row * DD + (nb + n) * 16 + c16] = o;
            }
        }
    }
}

// -------- kernel 2: fp16 gather table = aux(h @ lw) via MFMA ---------------
__global__ __launch_bounds__(256) void k_msg_aux(
    const float* __restrict__ h, const _Float16* __restrict__ Lt,
    __half* __restrict__ table)
{
    __shared__ float red[4][16];
    __shared__ float m0s[2][16];
    const int wv_ = threadIdx.x >> 6;
    const int lane = threadIdx.x & 63;
    const int g = lane >> 4, c16 = lane & 15;
    const int baseRow = blockIdx.x * 32 + (wv_ >> 1) * 16;
    const int nb = (wv_ & 1) * 4;
    const int arow = baseRow + c16;
    const bool rowOK = arow < NN;

    float4 f[8];
    const float4* hp = (const float4*)(h + (size_t)arow * DD) + g * 2;
    if (rowOK) {
#pragma unroll
        for (int ks = 0; ks < 4; ++ks) {
            f[2 * ks]     = hp[ks * 8];
            f[2 * ks + 1] = hp[ks * 8 + 1];
        }
    } else {
#pragma unroll
        for (int i = 0; i < 8; ++i) f[i] = float4{0.f, 0.f, 0.f, 0.f};
    }
    f16x8 ahi[4], alo[4];
#pragma unroll
    for (int ks = 0; ks < 4; ++ks) {
        const float q[8] = {f[2 * ks].x, f[2 * ks].y, f[2 * ks].z, f[2 * ks].w,
                            f[2 * ks + 1].x, f[2 * ks + 1].y, f[2 * ks + 1].z, f[2 * ks + 1].w};
#pragma unroll
        for (int j = 0; j < 8; ++j) {
            ahi[ks][j] = (_Float16)q[j];
            alo[ks][j] = (_Float16)(q[j] - (float)ahi[ks][j]);
        }
    }

    f32x4v acc[4];
#pragma unroll
    for (int n = 0; n < 4; ++n) acc[n] = f32x4v{0.f, 0.f, 0.f, 0.f};
#pragma unroll
    for (int ks = 0; ks < 4; ++ks) {
#pragma unroll
        for (int n = 0; n < 4; ++n) {
            const f16x8 bh = *(const f16x8*)(Lt + (size_t)((nb + n) * 16 + c16) * DD + ks * 32 + g * 8);
            acc[n] = __builtin_amdgcn_mfma_f32_16x16x32_f16(ahi[ks], bh, acc[n], 0, 0, 0);
            acc[n] = __builtin_amdgcn_mfma_f32_16x16x32_f16(alo[ks], bh, acc[n], 0, 0, 0);
        }
    }

#pragma unroll
    for (int r = 0; r < 4; ++r) {
        float part = 0.f;
#pragma unroll
        for (int n = 0; n < 4; ++n) {
            float sq = acc[n][r] * acc[n][r];
            if (nb == 0 && n == 0 && c16 == 0) sq = 0.f;
            part += sq;
        }
#pragma unroll
        for (int m = 1; m < 16; m <<= 1) part += __shfl_xor(part, m, 64);
        if (c16 == 0) red[wv_][4 * g + r] = part;
        if (nb == 0 && c16 == 0) m0s[wv_ >> 1][4 * g + r] = acc[0][r];
    }
    __syncthreads();
#pragma unroll
    for (int r = 0; r < 4; ++r) {
        const int row = baseRow + 4 * g + r;
        const float rn = 1.f / m0s[wv_ >> 1][4 * g + r];
        const float sum2 = red[wv_][4 * g + r] + red[wv_ ^ 1][4 * g + r];
        float kn = sum2 * rn * rn;
        kn = fminf(fmaxf(kn, 0.f), 0.9f);
        const float fh = 1.f / sqrtf(1.f - kn);
        if (row < NN) {
#pragma unroll
            for (int n = 0; n < 4; ++n) {
                const float val = (nb == 0 && n == 0 && c16 == 0) ? fh : acc[n][r] * rn;
                table[(size_t)row * DD + (nb + n) * 16 + c16] = __float2half(val);
            }
        }
    }
}

// -------- kernel 3a: gather pass A (cols 0-63, L2-resident half) -----------
// wave per node; lane = col. Computes ls, m_A = km/ls, c2A; spills state.
__global__ __launch_bounds__(256) void k_layer_a(
    const __half* __restrict__ table, const int* __restrict__ adj,
    const float* __restrict__ w, float* __restrict__ mA,
    float* __restrict__ lamW, float2* __restrict__ hdr)
{
    const int wave = threadIdx.x >> 6;
    const int lane = threadIdx.x & 63;
    const int node = blockIdx.x * 4 + wave;

    const int   av = adj[node * KK + (lane & 31)];
    const float wv = w[node * KK + (lane & 31)];

    const unsigned short* tb = (const unsigned short*)table;
    unsigned short vb[KK];
#pragma unroll
    for (int j = 0; j < KK; ++j) {
        const int idx = __shfl(av, j, 64);
        vb[j] = tb[(size_t)idx * DD + lane];
    }
    const float f = __half2float(table[(size_t)av * DD]);  // same line as gathers
    const float lam = wv * f;
    float ls = lam;
#pragma unroll
    for (int m = 1; m < 32; m <<= 1) ls += __shfl_xor(ls, m, 64);

    float km = 0.f;
#pragma unroll
    for (int j = 0; j < KK; ++j) {
        const float cj = __shfl(lam, j, 64);
        km = fmaf(cj, __half2float(*(const __half*)&vb[j]), km);
    }
    const float rl = 1.f / ls;
    const float m_ = km * rl;                  // lane0 = f-header col, garbage
    const float c2 = waveReduceSum(lane ? m_ * m_ : 0.f);
    mA[(size_t)node * 64 + lane] = m_;
    if (lane < KK) lamW[(size_t)node * KK + lane] = lam;
    if (lane == 0) hdr[node] = float2{ls, c2};
}

// -------- kernel 3b: gather pass B (cols 64-127) + finish ------------------
__global__ __launch_bounds__(256) void k_layer_b(
    const __half* __restrict__ table, const int* __restrict__ adj,
    const float* __restrict__ mA, const float* __restrict__ lamW,
    const float2* __restrict__ hdr, float* __restrict__ out)
{
    const int wave = threadIdx.x >> 6;
    const int lane = threadIdx.x & 63;
    const int node = blockIdx.x * 4 + wave;

    const int av = adj[node * KK + (lane & 31)];
    const unsigned short* tb = (const unsigned short*)table;
    unsigned short vb[KK];
#pragma unroll
    for (int j = 0; j < KK; ++j) {
        const int idx = __shfl(av, j, 64);
        vb[j] = tb[(size_t)idx * DD + 64 + lane];
    }
    const float lam = lamW[(size_t)node * KK + (lane & 31)];

    float km = 0.f;
#pragma unroll
    for (int j = 0; j < KK; ++j) {
        const float cj = __shfl(lam, j, 64);
        km = fmaf(cj, __half2float(*(const __half*)&vb[j]), km);
    }
    const float2 hd = hdr[node];
    const float rl = 1.f / hd.x;
    const float mB = km * rl;
    const float c2B = waveReduceSum(mB * mB);
    const float kn2 = fminf(hd.y + c2B, 0.9f);
    const float invs = 1.f / sqrtf(1.f - kn2);
    const float pd = invs + 1.f;
    const float mAv = mA[(size_t)node * 64 + lane];
    const float pA = lane ? seluf(mAv * invs / pd) : 0.f;
    const float pB = seluf(mB * invs / pd);
    const float pn = waveReduceSum(pA * pA + pB * pB);
    const float rdn = 1.f / (1.f - pn + 1e-6f);
    const float tm = sqrtf(1.f + 4.f * pn * rdn * rdn);
    out[(size_t)node * DD + lane]      = lane ? 2.f * pA * rdn : tm;
    out[(size_t)node * DD + 64 + lane] = 2.f * pB * rdn;
}

extern "C" void kernel_launch(void* const* d_in, const int* in_sizes, int n_in,
                              void* d_out, int out_size, void* d_ws, size_t ws_size,
                              hipStream_t stream) {
    const float* x     = (const float*)d_in[0];
    const int*   adj   = (const int*)d_in[1];
    const float* w     = (const float*)d_in[2];
    const float* lin_W = (const float*)d_in[3];
    const float* lin_b = (const float*)d_in[4];
    const float* M     = (const float*)d_in[5];
    float*  h     = (float*)d_out;                    // N*D fp32 (ping)
    char*   ws    = (char*)d_ws;
    __half*   table = (__half*)ws;                    //  7,680,000 B
    _Float16* Wt    = (_Float16*)(ws + 7680000);      //     65,536 B
    _Float16* Lt    = (_Float16*)(ws + 7745536);      //     32,768 B
    float*    mA    = (float*)(ws + 7778304);         //  7,680,000 B
    float*    lamW  = (float*)(ws + 15458304);        //  3,840,000 B
    float2*   hdr   = (float2*)(ws + 19298304);       //    240,000 B

    k_prep<<<256, 256, 0, stream>>>(lin_W, M, Wt, Lt);
    k_lin_exp<<<NB, 256, 0, stream>>>(x, Wt, lin_b, h);
    // layer 0
    k_msg_aux<<<NB, 256, 0, stream>>>(h, Lt, table);
    k_layer_a<<<NN / 4, 256, 0, stream>>>(table, adj, w, mA, lamW, hdr);
    k_layer_b<<<NN / 4, 256, 0, stream>>>(table, adj, mA, lamW, hdr, h);
    // layer 1
    k_msg_aux<<<NB, 256, 0, stream>>>(h, Lt, table);
    k_layer_a<<<NN / 4, 256, 0, stream>>>(table, adj, w, mA, lamW, hdr);
    k_layer_b<<<NN / 4, 256, 0, stream>>>(table, adj, mA, lamW, hdr, h);
}

// Round 9
// 124.849 us; speedup vs baseline: 1.4253x; 1.4253x over previous
//
#include <hip/hip_runtime.h>
#include <hip/hip_fp16.h>
#include <math.h>

#define NN 30000
#define KK 32
#define FF 256
#define DD 128
#define NB 938   // ceil(30000/32)

typedef _Float16 f16x8 __attribute__((ext_vector_type(8)));
typedef float f32x4v __attribute__((ext_vector_type(4)));

__device__ __forceinline__ float seluf(float x) {
    const float scale = 1.0507009873554804934193349852946f;
    const float alpha = 1.6732632423543772848170429916717f;
    return x > 0.f ? scale * x : scale * alpha * expm1f(x);
}

__device__ __forceinline__ float waveReduceSum(float v) {
#pragma unroll
    for (int m = 1; m < 64; m <<= 1) v += __shfl_xor(v, m, 64);
    return v;
}

// -------- kernel 0: transposed f16 weight tables ---------------------------
__global__ __launch_bounds__(256) void k_prep(
    const float* __restrict__ W, const float* __restrict__ M,
    _Float16* __restrict__ Wt, _Float16* __restrict__ Lt)
{
    const int b = blockIdx.x, t = threadIdx.x;
    if (b < 128) {
        Wt[b * FF + t] = (_Float16)W[t * DD + b];
    } else if (t < 128) {
        const int c = b - 128, k = t;
        const float v = (k == 0 && c == 0) ? 1.f
                      : ((k >= 1 && c >= 1) ? M[(k - 1) * 127 + (c - 1)] : 0.f);
        Lt[c * DD + k] = (_Float16)v;
    }
}

// -------- kernel 1: table = msg_aux(normalize(expmap(selu(x@W+b))) @ lw) ---
// Fused: phase 1 computes the h tile (32 rows) into LDS; phase 2 runs the
// msg MFMA + Klein/f-header epilogue straight out of LDS. h never hits HBM.
__global__ __launch_bounds__(256) void k_lin_exp_msg(
    const float* __restrict__ x, const _Float16* __restrict__ Wt,
    const float* __restrict__ b, const _Float16* __restrict__ Lt,
    __half* __restrict__ table)
{
    __shared__ float hs[32][132];    // padded: 132*4=528 B rows (16B aligned)
    __shared__ float red[4][16];
    __shared__ float m0s[2][16];
    const int wv_ = threadIdx.x >> 6;
    const int lane = threadIdx.x & 63;
    const int g = lane >> 4, c16 = lane & 15;
    const int rowHalf = wv_ >> 1;
    const int baseRow = blockIdx.x * 32 + rowHalf * 16;
    const int nb = (wv_ & 1) * 4;
    const int arow = baseRow + c16;
    const bool rowOK = arow < NN;

    // ---- phase 1: h = normalize(expmap(selu(x@W+b))) ----
    f16x8 ahi[8], alo[8];
    const float4* xp = (const float4*)(x + (size_t)arow * FF) + g * 2;
#pragma unroll
    for (int c = 0; c < 2; ++c) {       // 2 chunks of 4 ks -> lower VGPR peak
        float4 f[8];
        if (rowOK) {
#pragma unroll
            for (int kk = 0; kk < 4; ++kk) {
                f[2 * kk]     = xp[(c * 4 + kk) * 8];
                f[2 * kk + 1] = xp[(c * 4 + kk) * 8 + 1];
            }
        } else {
#pragma unroll
            for (int i = 0; i < 8; ++i) f[i] = float4{0.f, 0.f, 0.f, 0.f};
        }
#pragma unroll
        for (int kk = 0; kk < 4; ++kk) {
            const int ks = c * 4 + kk;
            const float q[8] = {f[2 * kk].x, f[2 * kk].y, f[2 * kk].z, f[2 * kk].w,
                                f[2 * kk + 1].x, f[2 * kk + 1].y, f[2 * kk + 1].z, f[2 * kk + 1].w};
#pragma unroll
            for (int j = 0; j < 8; ++j) {
                ahi[ks][j] = (_Float16)q[j];
                alo[ks][j] = (_Float16)(q[j] - (float)ahi[ks][j]);
            }
        }
    }

    f32x4v acc[4];
#pragma unroll
    for (int n = 0; n < 4; ++n) acc[n] = f32x4v{0.f, 0.f, 0.f, 0.f};
#pragma unroll
    for (int ks = 0; ks < 8; ++ks) {
#pragma unroll
        for (int n = 0; n < 4; ++n) {
            const f16x8 bh = *(const f16x8*)(Wt + (size_t)((nb + n) * 16 + c16) * FF + ks * 32 + g * 8);
            acc[n] = __builtin_amdgcn_mfma_f32_16x16x32_f16(ahi[ks], bh, acc[n], 0, 0, 0);
            acc[n] = __builtin_amdgcn_mfma_f32_16x16x32_f16(alo[ks], bh, acc[n], 0, 0, 0);
        }
    }

    float bias[4];
#pragma unroll
    for (int n = 0; n < 4; ++n) bias[n] = b[(nb + n) * 16 + c16];

    float vv[4][4];
#pragma unroll
    for (int r = 0; r < 4; ++r) {
        float part = 0.f;
#pragma unroll
        for (int n = 0; n < 4; ++n) {
            vv[r][n] = seluf(acc[n][r] + bias[n]);
            float sq = vv[r][n] * vv[r][n];
            if (nb == 0 && n == 0 && c16 == 0) sq = 0.f;   // exclude d=0
            part += sq;
        }
#pragma unroll
        for (int m = 1; m < 16; m <<= 1) part += __shfl_xor(part, m, 64);
        if (c16 == 0) red[wv_][4 * g + r] = part;
    }
    __syncthreads();
#pragma unroll
    for (int r = 0; r < 4; ++r) {
        const int lrow = rowHalf * 16 + 4 * g + r;
        const float ldv = red[wv_][4 * g + r] + red[wv_ ^ 1][4 * g + r];
        const float nd = sqrtf(fmaxf(ldv + 1e-9f, 1e-10f));
        const float t  = fminf(nd, 1.0f);
        const float sc = sinhf(t) / nd;
        const float tm = sqrtf(1.f + sc * sc * ldv);
#pragma unroll
        for (int n = 0; n < 4; ++n) {
            const float o = (nb == 0 && n == 0 && c16 == 0) ? tm : sc * vv[r][n];
            hs[lrow][(nb + n) * 16 + c16] = o;
        }
    }
    __syncthreads();

    // ---- phase 2: msg = h @ lw; table = Klein coords + f-header ----
    f16x8 mhi[4], mlo[4];
#pragma unroll
    for (int ks = 0; ks < 4; ++ks) {
        const float* hp = &hs[rowHalf * 16 + c16][ks * 32 + g * 8];
        const float4 f0 = *(const float4*)hp;
        const float4 f1 = *(const float4*)(hp + 4);
        const float q[8] = {f0.x, f0.y, f0.z, f0.w, f1.x, f1.y, f1.z, f1.w};
#pragma unroll
        for (int j = 0; j < 8; ++j) {
            mhi[ks][j] = (_Float16)q[j];
            mlo[ks][j] = (_Float16)(q[j] - (float)mhi[ks][j]);
        }
    }

#pragma unroll
    for (int n = 0; n < 4; ++n) acc[n] = f32x4v{0.f, 0.f, 0.f, 0.f};
#pragma unroll
    for (int ks = 0; ks < 4; ++ks) {
#pragma unroll
        for (int n = 0; n < 4; ++n) {
            const f16x8 bh = *(const f16x8*)(Lt + (size_t)((nb + n) * 16 + c16) * DD + ks * 32 + g * 8);
            acc[n] = __builtin_amdgcn_mfma_f32_16x16x32_f16(mhi[ks], bh, acc[n], 0, 0, 0);
            acc[n] = __builtin_amdgcn_mfma_f32_16x16x32_f16(mlo[ks], bh, acc[n], 0, 0, 0);
        }
    }

#pragma unroll
    for (int r = 0; r < 4; ++r) {
        float part = 0.f;
#pragma unroll
        for (int n = 0; n < 4; ++n) {
            float sq = acc[n][r] * acc[n][r];
            if (nb == 0 && n == 0 && c16 == 0) sq = 0.f;   // time slot
            part += sq;
        }
#pragma unroll
        for (int m = 1; m < 16; m <<= 1) part += __shfl_xor(part, m, 64);
        if (c16 == 0) red[wv_][4 * g + r] = part;
        if (nb == 0 && c16 == 0) m0s[rowHalf][4 * g + r] = acc[0][r];
    }
    __syncthreads();
#pragma unroll
    for (int r = 0; r < 4; ++r) {
        const int row = baseRow + 4 * g + r;
        const float rn = 1.f / m0s[rowHalf][4 * g + r];
        const float sum2 = red[wv_][4 * g + r] + red[wv_ ^ 1][4 * g + r];
        float kn = sum2 * rn * rn;
        kn = fminf(fmaxf(kn, 0.f), 0.9f);
        const float fh = 1.f / sqrtf(1.f - kn);
        if (row < NN) {
#pragma unroll
            for (int n = 0; n < 4; ++n) {
                const float val = (nb == 0 && n == 0 && c16 == 0) ? fh : acc[n][r] * rn;
                table[(size_t)row * DD + (nb + n) * 16 + c16] = __float2half(val);
            }
        }
    }
}

// -------- kernel 2: fp16 gather table = aux(h @ lw) via MFMA (layer 1) -----
__global__ __launch_bounds__(256) void k_msg_aux(
    const float* __restrict__ h, const _Float16* __restrict__ Lt,
    __half* __restrict__ table)
{
    __shared__ float red[4][16];
    __shared__ float m0s[2][16];
    const int wv_ = threadIdx.x >> 6;
    const int lane = threadIdx.x & 63;
    const int g = lane >> 4, c16 = lane & 15;
    const int baseRow = blockIdx.x * 32 + (wv_ >> 1) * 16;
    const int nb = (wv_ & 1) * 4;
    const int arow = baseRow + c16;
    const bool rowOK = arow < NN;

    float4 f[8];
    const float4* hp = (const float4*)(h + (size_t)arow * DD) + g * 2;
    if (rowOK) {
#pragma unroll
        for (int ks = 0; ks < 4; ++ks) {
            f[2 * ks]     = hp[ks * 8];
            f[2 * ks + 1] = hp[ks * 8 + 1];
        }
    } else {
#pragma unroll
        for (int i = 0; i < 8; ++i) f[i] = float4{0.f, 0.f, 0.f, 0.f};
    }
    f16x8 ahi[4], alo[4];
#pragma unroll
    for (int ks = 0; ks < 4; ++ks) {
        const float q[8] = {f[2 * ks].x, f[2 * ks].y, f[2 * ks].z, f[2 * ks].w,
                            f[2 * ks + 1].x, f[2 * ks + 1].y, f[2 * ks + 1].z, f[2 * ks + 1].w};
#pragma unroll
        for (int j = 0; j < 8; ++j) {
            ahi[ks][j] = (_Float16)q[j];
            alo[ks][j] = (_Float16)(q[j] - (float)ahi[ks][j]);
        }
    }

    f32x4v acc[4];
#pragma unroll
    for (int n = 0; n < 4; ++n) acc[n] = f32x4v{0.f, 0.f, 0.f, 0.f};
#pragma unroll
    for (int ks = 0; ks < 4; ++ks) {
#pragma unroll
        for (int n = 0; n < 4; ++n) {
            const f16x8 bh = *(const f16x8*)(Lt + (size_t)((nb + n) * 16 + c16) * DD + ks * 32 + g * 8);
            acc[n] = __builtin_amdgcn_mfma_f32_16x16x32_f16(ahi[ks], bh, acc[n], 0, 0, 0);
            acc[n] = __builtin_amdgcn_mfma_f32_16x16x32_f16(alo[ks], bh, acc[n], 0, 0, 0);
        }
    }

#pragma unroll
    for (int r = 0; r < 4; ++r) {
        float part = 0.f;
#pragma unroll
        for (int n = 0; n < 4; ++n) {
            float sq = acc[n][r] * acc[n][r];
            if (nb == 0 && n == 0 && c16 == 0) sq = 0.f;
            part += sq;
        }
#pragma unroll
        for (int m = 1; m < 16; m <<= 1) part += __shfl_xor(part, m, 64);
        if (c16 == 0) red[wv_][4 * g + r] = part;
        if (nb == 0 && c16 == 0) m0s[wv_ >> 1][4 * g + r] = acc[0][r];
    }
    __syncthreads();
#pragma unroll
    for (int r = 0; r < 4; ++r) {
        const int row = baseRow + 4 * g + r;
        const float rn = 1.f / m0s[wv_ >> 1][4 * g + r];
        const float sum2 = red[wv_][4 * g + r] + red[wv_ ^ 1][4 * g + r];
        float kn = sum2 * rn * rn;
        kn = fminf(fmaxf(kn, 0.f), 0.9f);
        const float fh = 1.f / sqrtf(1.f - kn);
        if (row < NN) {
#pragma unroll
            for (int n = 0; n < 4; ++n) {
                const float val = (nb == 0 && n == 0 && c16 == 0) ? fh : acc[n][r] * rn;
                table[(size_t)row * DD + (nb + n) * 16 + c16] = __float2half(val);
            }
        }
    }
}

// -------- kernel 3: gather + weighted mean + activation + normalize --------
// one wave per node; all 32 row-gathers prefetched into registers (round-7).
__global__ __launch_bounds__(256) void k_layer(
    const __half* __restrict__ table, const int* __restrict__ adj,
    const float* __restrict__ w, float* __restrict__ out)
{
    const int wave = threadIdx.x >> 6;
    const int lane = threadIdx.x & 63;
    const int node = blockIdx.x * 4 + wave;

    const int   av = adj[node * KK + (lane & 31)];
    const float wv = w[node * KK + (lane & 31)];

    unsigned int vbits[32];
#pragma unroll
    for (int j = 0; j < KK; ++j) {
        const int idx = __shfl(av, j, 64);
        vbits[j] = *(const unsigned int*)(table + (size_t)idx * DD + lane * 2);
    }

    const float f  = __half2float(table[(size_t)av * DD]);
    const float lam = wv * f;
    float ls = lam;
#pragma unroll
    for (int m = 1; m < 32; m <<= 1) ls += __shfl_xor(ls, m, 64);

    float km0 = 0.f, km1 = 0.f;
#pragma unroll
    for (int j = 0; j < KK; ++j) {
        const float cj = __shfl(lam, j, 64);
        const __half2 hh = *(const __half2*)&vbits[j];
        const float2 v = __half22float2(hh);
        km0 = fmaf(cj, v.x, km0);   // lane0.x holds f-header, masked below
        km1 = fmaf(cj, v.y, km1);
    }
    const float rl = 1.f / ls;
    const float m0 = km0 * rl;
    const float m1 = km1 * rl;
    float c2 = (lane ? m0 * m0 : 0.f) + m1 * m1;
    const float kn2 = fminf(waveReduceSum(c2), 0.9f);
    const float invs = 1.f / sqrtf(1.f - kn2);
    const float pd = invs + 1.f;
    const float p0 = lane ? seluf(m0 * invs / pd) : 0.f;
    const float p1 = seluf(m1 * invs / pd);
    float pc = p0 * p0 + p1 * p1;
    const float pn = waveReduceSum(pc);
    const float rdn = 1.f / (1.f - pn + 1e-6f);
    const float tm = sqrtf(1.f + 4.f * pn * rdn * rdn);
    float2 o;
    o.x = lane ? 2.f * p0 * rdn : tm;
    o.y = 2.f * p1 * rdn;
    *(float2*)(out + (size_t)node * DD + lane * 2) = o;
}

extern "C" void kernel_launch(void* const* d_in, const int* in_sizes, int n_in,
                              void* d_out, int out_size, void* d_ws, size_t ws_size,
                              hipStream_t stream) {
    const float* x     = (const float*)d_in[0];
    const int*   adj   = (const int*)d_in[1];
    const float* w     = (const float*)d_in[2];
    const float* lin_W = (const float*)d_in[3];
    const float* lin_b = (const float*)d_in[4];
    const float* M     = (const float*)d_in[5];
    float*  h     = (float*)d_out;                 // N*D fp32 (scratch + final)
    char*   ws    = (char*)d_ws;
    __half*   table = (__half*)ws;                 // 7,680,000 B
    _Float16* Wt    = (_Float16*)(ws + 7680000);   //    65,536 B
    _Float16* Lt    = (_Float16*)(ws + 7745536);   //    32,768 B

    k_prep<<<256, 256, 0, stream>>>(lin_W, M, Wt, Lt);
    // layer 0 table directly from x (h stays in LDS)
    k_lin_exp_msg<<<NB, 256, 0, stream>>>(x, Wt, lin_b, Lt, table);
    k_layer<<<NN / 4, 256, 0, stream>>>(table, adj, w, h);
    // layer 1
    k_msg_aux<<<NB, 256, 0, stream>>>(h, Lt, table);
    k_layer<<<NN / 4, 256, 0, stream>>>(table, adj, w, h);
}

// Round 10
// 123.817 us; speedup vs baseline: 1.4372x; 1.0083x over previous
//
#include <hip/hip_runtime.h>
#include <hip/hip_fp16.h>
#include <math.h>

#define NN 30000
#define KK 32
#define FF 256
#define DD 128
#define NB16 1875   // 30000 / 16 exactly

typedef _Float16 f16x8 __attribute__((ext_vector_type(8)));
typedef float f32x4v __attribute__((ext_vector_type(4)));

__device__ __forceinline__ float seluf(float x) {
    const float scale = 1.0507009873554804934193349852946f;
    const float alpha = 1.6732632423543772848170429916717f;
    return x > 0.f ? scale * x : scale * alpha * expm1f(x);
}

__device__ __forceinline__ float waveReduceSum(float v) {
#pragma unroll
    for (int m = 1; m < 64; m <<= 1) v += __shfl_xor(v, m, 64);
    return v;
}

// -------- kernel 0: transposed f16 weight tables ---------------------------
__global__ __launch_bounds__(256) void k_prep(
    const float* __restrict__ W, const float* __restrict__ M,
    _Float16* __restrict__ Wt, _Float16* __restrict__ Lt)
{
    const int b = blockIdx.x, t = threadIdx.x;
    if (b < 128) {
        Wt[b * FF + t] = (_Float16)W[t * DD + b];
    } else if (t < 128) {
        const int c = b - 128, k = t;
        const float v = (k == 0 && c == 0) ? 1.f
                      : ((k >= 1 && c >= 1) ? M[(k - 1) * 127 + (c - 1)] : 0.f);
        Lt[c * DD + k] = (_Float16)v;
    }
}

// -------- kernel 1: table = msg_aux(normalize(expmap(selu(x@W+b))) @ lw) ---
// 2 waves / 16 rows per block. Wave wv_ owns cols wv_*64..+63 (4 n-tiles).
// Phase 1: single-f16 A (x@W); phase 2: hi/lo exact-A msg MFMA from LDS.
__global__ __launch_bounds__(128) void k_lin_exp_msg(
    const float* __restrict__ x, const _Float16* __restrict__ Wt,
    const float* __restrict__ b, const _Float16* __restrict__ Lt,
    __half* __restrict__ table)
{
    __shared__ float hs[16][132];
    __shared__ float red[2][16];
    __shared__ float m0s[16];
    const int wv_ = threadIdx.x >> 6;
    const int lane = threadIdx.x & 63;
    const int g = lane >> 4, c16 = lane & 15;
    const int baseRow = blockIdx.x * 16;
    const int nb = wv_ * 4;
    const int arow = baseRow + c16;   // always < NN (30000 = 16*1875)

    // ---- phase 1: h = normalize(expmap(selu(x@W+b))) ----
    f16x8 ahi[8];
    const float4* xp = (const float4*)(x + (size_t)arow * FF) + g * 2;
#pragma unroll
    for (int c = 0; c < 2; ++c) {
        float4 f[8];
#pragma unroll
        for (int kk = 0; kk < 4; ++kk) {
            f[2 * kk]     = xp[(c * 4 + kk) * 8];
            f[2 * kk + 1] = xp[(c * 4 + kk) * 8 + 1];
        }
#pragma unroll
        for (int kk = 0; kk < 4; ++kk) {
            const int ks = c * 4 + kk;
            const float q[8] = {f[2 * kk].x, f[2 * kk].y, f[2 * kk].z, f[2 * kk].w,
                                f[2 * kk + 1].x, f[2 * kk + 1].y, f[2 * kk + 1].z, f[2 * kk + 1].w};
#pragma unroll
            for (int j = 0; j < 8; ++j) ahi[ks][j] = (_Float16)q[j];
        }
    }

    f32x4v acc[4];
#pragma unroll
    for (int n = 0; n < 4; ++n) acc[n] = f32x4v{0.f, 0.f, 0.f, 0.f};
#pragma unroll
    for (int ks = 0; ks < 8; ++ks) {
#pragma unroll
        for (int n = 0; n < 4; ++n) {
            const f16x8 bh = *(const f16x8*)(Wt + (size_t)((nb + n) * 16 + c16) * FF + ks * 32 + g * 8);
            acc[n] = __builtin_amdgcn_mfma_f32_16x16x32_f16(ahi[ks], bh, acc[n], 0, 0, 0);
        }
    }

    float bias[4];
#pragma unroll
    for (int n = 0; n < 4; ++n) bias[n] = b[(nb + n) * 16 + c16];

    float vv[4][4];
#pragma unroll
    for (int r = 0; r < 4; ++r) {
        float part = 0.f;
#pragma unroll
        for (int n = 0; n < 4; ++n) {
            vv[r][n] = seluf(acc[n][r] + bias[n]);
            float sq = vv[r][n] * vv[r][n];
            if (nb == 0 && n == 0 && c16 == 0) sq = 0.f;   // exclude d=0
            part += sq;
        }
#pragma unroll
        for (int m = 1; m < 16; m <<= 1) part += __shfl_xor(part, m, 64);
        if (c16 == 0) red[wv_][4 * g + r] = part;
    }
    __syncthreads();
#pragma unroll
    for (int r = 0; r < 4; ++r) {
        const int lrow = 4 * g + r;
        const float ldv = red[0][lrow] + red[1][lrow];
        const float nd = sqrtf(fmaxf(ldv + 1e-9f, 1e-10f));
        const float t  = fminf(nd, 1.0f);
        const float sc = sinhf(t) / nd;
        const float tm = sqrtf(1.f + sc * sc * ldv);
#pragma unroll
        for (int n = 0; n < 4; ++n) {
            const float o = (nb == 0 && n == 0 && c16 == 0) ? tm : sc * vv[r][n];
            hs[lrow][(nb + n) * 16 + c16] = o;
        }
    }
    __syncthreads();

    // ---- phase 2: msg = h @ lw (exact A via hi/lo); Klein + f-header ----
    f16x8 mhi[4], mlo[4];
#pragma unroll
    for (int ks = 0; ks < 4; ++ks) {
        const float* hp = &hs[c16][ks * 32 + g * 8];
        const float4 f0 = *(const float4*)hp;
        const float4 f1 = *(const float4*)(hp + 4);
        const float q[8] = {f0.x, f0.y, f0.z, f0.w, f1.x, f1.y, f1.z, f1.w};
#pragma unroll
        for (int j = 0; j < 8; ++j) {
            mhi[ks][j] = (_Float16)q[j];
            mlo[ks][j] = (_Float16)(q[j] - (float)mhi[ks][j]);
        }
    }

#pragma unroll
    for (int n = 0; n < 4; ++n) acc[n] = f32x4v{0.f, 0.f, 0.f, 0.f};
#pragma unroll
    for (int ks = 0; ks < 4; ++ks) {
#pragma unroll
        for (int n = 0; n < 4; ++n) {
            const f16x8 bh = *(const f16x8*)(Lt + (size_t)((nb + n) * 16 + c16) * DD + ks * 32 + g * 8);
            acc[n] = __builtin_amdgcn_mfma_f32_16x16x32_f16(mhi[ks], bh, acc[n], 0, 0, 0);
            acc[n] = __builtin_amdgcn_mfma_f32_16x16x32_f16(mlo[ks], bh, acc[n], 0, 0, 0);
        }
    }

#pragma unroll
    for (int r = 0; r < 4; ++r) {
        float part = 0.f;
#pragma unroll
        for (int n = 0; n < 4; ++n) {
            float sq = acc[n][r] * acc[n][r];
            if (nb == 0 && n == 0 && c16 == 0) sq = 0.f;   // time slot
            part += sq;
        }
#pragma unroll
        for (int m = 1; m < 16; m <<= 1) part += __shfl_xor(part, m, 64);
        if (c16 == 0) red[wv_][4 * g + r] = part;
        if (nb == 0 && c16 == 0) m0s[4 * g + r] = acc[0][r];
    }
    __syncthreads();
#pragma unroll
    for (int r = 0; r < 4; ++r) {
        const int lrow = 4 * g + r;
        const int row = baseRow + lrow;
        const float rn = 1.f / m0s[lrow];
        const float sum2 = red[0][lrow] + red[1][lrow];
        float kn = sum2 * rn * rn;
        kn = fminf(fmaxf(kn, 0.f), 0.9f);
        const float fh = 1.f / sqrtf(1.f - kn);
#pragma unroll
        for (int n = 0; n < 4; ++n) {
            const float val = (nb == 0 && n == 0 && c16 == 0) ? fh : acc[n][r] * rn;
            table[(size_t)row * DD + (nb + n) * 16 + c16] = __float2half(val);
        }
    }
}

// -------- kernel 2: fp16 gather table = aux(h @ lw) via MFMA (layer 1) -----
// 2 waves / 16 rows per block; hi/lo exact A.
__global__ __launch_bounds__(128) void k_msg_aux(
    const float* __restrict__ h, const _Float16* __restrict__ Lt,
    __half* __restrict__ table)
{
    __shared__ float red[2][16];
    __shared__ float m0s[16];
    const int wv_ = threadIdx.x >> 6;
    const int lane = threadIdx.x & 63;
    const int g = lane >> 4, c16 = lane & 15;
    const int baseRow = blockIdx.x * 16;
    const int nb = wv_ * 4;
    const int arow = baseRow + c16;

    float4 f[8];
    const float4* hp = (const float4*)(h + (size_t)arow * DD) + g * 2;
#pragma unroll
    for (int ks = 0; ks < 4; ++ks) {
        f[2 * ks]     = hp[ks * 8];
        f[2 * ks + 1] = hp[ks * 8 + 1];
    }
    f16x8 ahi[4], alo[4];
#pragma unroll
    for (int ks = 0; ks < 4; ++ks) {
        const float q[8] = {f[2 * ks].x, f[2 * ks].y, f[2 * ks].z, f[2 * ks].w,
                            f[2 * ks + 1].x, f[2 * ks + 1].y, f[2 * ks + 1].z, f[2 * ks + 1].w};
#pragma unroll
        for (int j = 0; j < 8; ++j) {
            ahi[ks][j] = (_Float16)q[j];
            alo[ks][j] = (_Float16)(q[j] - (float)ahi[ks][j]);
        }
    }

    f32x4v acc[4];
#pragma unroll
    for (int n = 0; n < 4; ++n) acc[n] = f32x4v{0.f, 0.f, 0.f, 0.f};
#pragma unroll
    for (int ks = 0; ks < 4; ++ks) {
#pragma unroll
        for (int n = 0; n < 4; ++n) {
            const f16x8 bh = *(const f16x8*)(Lt + (size_t)((nb + n) * 16 + c16) * DD + ks * 32 + g * 8);
            acc[n] = __builtin_amdgcn_mfma_f32_16x16x32_f16(ahi[ks], bh, acc[n], 0, 0, 0);
            acc[n] = __builtin_amdgcn_mfma_f32_16x16x32_f16(alo[ks], bh, acc[n], 0, 0, 0);
        }
    }

#pragma unroll
    for (int r = 0; r < 4; ++r) {
        float part = 0.f;
#pragma unroll
        for (int n = 0; n < 4; ++n) {
            float sq = acc[n][r] * acc[n][r];
            if (nb == 0 && n == 0 && c16 == 0) sq = 0.f;
            part += sq;
        }
#pragma unroll
        for (int m = 1; m < 16; m <<= 1) part += __shfl_xor(part, m, 64);
        if (c16 == 0) red[wv_][4 * g + r] = part;
        if (nb == 0 && c16 == 0) m0s[4 * g + r] = acc[0][r];
    }
    __syncthreads();
#pragma unroll
    for (int r = 0; r < 4; ++r) {
        const int lrow = 4 * g + r;
        const int row = baseRow + lrow;
        const float rn = 1.f / m0s[lrow];
        const float sum2 = red[0][lrow] + red[1][lrow];
        float kn = sum2 * rn * rn;
        kn = fminf(fmaxf(kn, 0.f), 0.9f);
        const float fh = 1.f / sqrtf(1.f - kn);
#pragma unroll
        for (int n = 0; n < 4; ++n) {
            const float val = (nb == 0 && n == 0 && c16 == 0) ? fh : acc[n][r] * rn;
            table[(size_t)row * DD + (nb + n) * 16 + c16] = __float2half(val);
        }
    }
}

// -------- kernel 3: gather + weighted mean + activation + normalize --------
// one wave per node; all 32 row-gathers prefetched into registers.
__global__ __launch_bounds__(256) void k_layer(
    const __half* __restrict__ table, const int* __restrict__ adj,
    const float* __restrict__ w, float* __restrict__ out)
{
    const int wave = threadIdx.x >> 6;
    const int lane = threadIdx.x & 63;
    const int node = blockIdx.x * 4 + wave;

    const int   av = adj[node * KK + (lane & 31)];
    const float wv = w[node * KK + (lane & 31)];

    unsigned int vbits[32];
#pragma unroll
    for (int j = 0; j < KK; ++j) {
        const int idx = __shfl(av, j, 64);
        vbits[j] = *(const unsigned int*)(table + (size_t)idx * DD + lane * 2);
    }

    const float f  = __half2float(table[(size_t)av * DD]);
    const float lam = wv * f;
    float ls = lam;
#pragma unroll
    for (int m = 1; m < 32; m <<= 1) ls += __shfl_xor(ls, m, 64);

    float km0 = 0.f, km1 = 0.f;
#pragma unroll
    for (int j = 0; j < KK; ++j) {
        const float cj = __shfl(lam, j, 64);
        const __half2 hh = *(const __half2*)&vbits[j];
        const float2 v = __half22float2(hh);
        km0 = fmaf(cj, v.x, km0);   // lane0.x holds f-header, masked below
        km1 = fmaf(cj, v.y, km1);
    }
    const float rl = 1.f / ls;
    const float m0 = km0 * rl;
    const float m1 = km1 * rl;
    float c2 = (lane ? m0 * m0 : 0.f) + m1 * m1;
    const float kn2 = fminf(waveReduceSum(c2), 0.9f);
    const float invs = 1.f / sqrtf(1.f - kn2);
    const float pd = invs + 1.f;
    const float p0 = lane ? seluf(m0 * invs / pd) : 0.f;
    const float p1 = seluf(m1 * invs / pd);
    float pc = p0 * p0 + p1 * p1;
    const float pn = waveReduceSum(pc);
    const float rdn = 1.f / (1.f - pn + 1e-6f);
    const float tm = sqrtf(1.f + 4.f * pn * rdn * rdn);
    float2 o;
    o.x = lane ? 2.f * p0 * rdn : tm;
    o.y = 2.f * p1 * rdn;
    *(float2*)(out + (size_t)node * DD + lane * 2) = o;
}

extern "C" void kernel_launch(void* const* d_in, const int* in_sizes, int n_in,
                              void* d_out, int out_size, void* d_ws, size_t ws_size,
                              hipStream_t stream) {
    const float* x     = (const float*)d_in[0];
    const int*   adj   = (const int*)d_in[1];
    const float* w     = (const float*)d_in[2];
    const float* lin_W = (const float*)d_in[3];
    const float* lin_b = (const float*)d_in[4];
    const float* M     = (const float*)d_in[5];
    float*  h     = (float*)d_out;                 // N*D fp32 (scratch + final)
    char*   ws    = (char*)d_ws;
    __half*   table = (__half*)ws;                 // 7,680,000 B
    _Float16* Wt    = (_Float16*)(ws + 7680000);   //    65,536 B
    _Float16* Lt    = (_Float16*)(ws + 7745536);   //    32,768 B

    k_prep<<<256, 256, 0, stream>>>(lin_W, M, Wt, Lt);
    // layer 0 table directly from x (h stays in LDS)
    k_lin_exp_msg<<<NB16, 128, 0, stream>>>(x, Wt, lin_b, Lt, table);
    k_layer<<<NN / 4, 256, 0, stream>>>(table, adj, w, h);
    // layer 1
    k_msg_aux<<<NB16, 128, 0, stream>>>(h, Lt, table);
    k_layer<<<NN / 4, 256, 0, stream>>>(table, adj, w, h);
}